// Round 3
// baseline (3584.121 us; speedup 1.0000x reference)
//
#include <hip/hip_runtime.h>

// ---------------------------------------------------------------------------
// LSTM (B=128, T=512, D=512, H=1024, O=256), forget bias 1.0
//   prep:    f16 conversions/transposes/fragment-packing of weights
//   phase1:  xw = X @ W_x + b  (f16 MFMA GEMM, 65536x512x4096) -> ws
//   phase2:  persistent cooperative kernel, 512 sequential steps.
//            8 teams x 16 batch rows; 32 blocks/team each owning 32 hidden
//            units (128 gate cols). W_h fragments live in VGPRs/AGPRs.
//            h exchanged as TAGGED u32 words ((t+1)<<16 | f16) through the
//            Infinity Cache (sc0 sc1): producers fire-and-forget one store,
//            consumers poll their own words until tags match -> ONE coherent
//            round trip per step instead of three (drain + flag + load).
//   phase3:  logits = lstm_out @ W_out + b_out (f16 MFMA GEMM)
// ---------------------------------------------------------------------------

typedef _Float16 f16;
typedef _Float16 half8 __attribute__((ext_vector_type(8)));
typedef float floatx4 __attribute__((ext_vector_type(4)));
typedef unsigned u32x4 __attribute__((ext_vector_type(4)));

#define AS1 __attribute__((address_space(1)))
#define AS3 __attribute__((address_space(3)))

__device__ __forceinline__ void gload_lds16(const void* g, void* l) {
  __builtin_amdgcn_global_load_lds((const AS1 void*)g, (AS3 void*)l, 16, 0, 0);
}

// issue two coherent dwordx4 loads (32B granule) at p, p+16B; NO wait here
__device__ __forceinline__ void load_granule_coh(const unsigned* p, u32x4& a, u32x4& b) {
  asm volatile("global_load_dwordx4 %0, %2, off sc0 sc1\n\t"
               "global_load_dwordx4 %1, %2, off offset:16 sc0 sc1"
               : "=&v"(a), "=&v"(b) : "v"(p) : "memory");
}
__device__ __forceinline__ void store_u32_coh(unsigned* p, unsigned v) {
  asm volatile("global_store_dword %0, %1, off sc0 sc1" :: "v"(p), "v"(v) : "memory");
}

__device__ __forceinline__ float sigm(float x) { return 1.f / (1.f + __expf(-x)); }
__device__ __forceinline__ float tanh_fast(float x) {
  float ax = fabsf(x);
  float e = __expf(2.f * ax);          // overflows to +inf for big |x| -> t=1 exactly
  float t = 1.f - 2.f / (e + 1.f);
  return copysignf(t, x);
}

// ---------------- workspace layout ----------------
static constexpr size_t XW_OFF  = 0;
static constexpr size_t XW_BY   = (size_t)65536 * 4096 * 2;        // 536870912
static constexpr size_t L16_OFF = XW_OFF + XW_BY;                  // lstm_out f16 (aliases in16)
static constexpr size_t L16_BY  = (size_t)65536 * 1024 * 2;        // 134217728
static constexpr size_t IN16_OFF = L16_OFF;                        // inputs f16 (phase1 only)
static constexpr size_t WXT_OFF = L16_OFF + L16_BY;
static constexpr size_t WXT_BY  = (size_t)4096 * 512 * 2;
static constexpr size_t WOT_OFF = WXT_OFF + WXT_BY;
static constexpr size_t WOT_BY  = (size_t)256 * 1024 * 2;
static constexpr size_t WPK_OFF = WOT_OFF + WOT_BY;
static constexpr size_t WPK_BY  = (size_t)524288 * 8 * 2;          // W_h frag-packed
static constexpr size_t TH_OFF  = WPK_OFF + WPK_BY;
static constexpr size_t TH_BY   = (size_t)2 * 128 * 1024 * 4;      // tagged h ping-pong (u32)
static constexpr size_t WS_NEED = TH_OFF + TH_BY;

// ---------------- prep kernels ----------------
__global__ __launch_bounds__(256) void conv_f32_to_f16(const float* __restrict__ in,
                                                       f16* __restrict__ out) {
  size_t i = (size_t)blockIdx.x * 256 + threadIdx.x;
  const float4* in4 = (const float4*)in;
  float4 a = in4[i * 2], b = in4[i * 2 + 1];
  half8 v = {(f16)a.x, (f16)a.y, (f16)a.z, (f16)a.w,
             (f16)b.x, (f16)b.y, (f16)b.z, (f16)b.w};
  *(half8*)(out + i * 8) = v;
}

// out[c][r] = (f16)in[r][c]; grid = (C/64, R/64)
__global__ __launch_bounds__(256) void transpose_f32_to_f16(const float* __restrict__ in,
                                                            f16* __restrict__ out,
                                                            int R, int C) {
  __shared__ float tile[64][65];
  int tx = threadIdx.x & 63, ty = threadIdx.x >> 6;
  int c0 = blockIdx.x * 64, r0 = blockIdx.y * 64;
#pragma unroll
  for (int q = 0; q < 16; ++q) {
    int r = q * 4 + ty;
    tile[r][tx] = in[(size_t)(r0 + r) * C + c0 + tx];
  }
  __syncthreads();
#pragma unroll
  for (int q = 0; q < 16; ++q) {
    int oc = q * 4 + ty;
    out[(size_t)(c0 + oc) * R + r0 + tx] = (f16)tile[tx][oc];
  }
}

// Pack W_h (rows 512..1535 of W_lstm) into per-(colblock,wave,ni,ks,lane) f16x8
// fragments matching the phase-2 MFMA B-operand layout (n=lane&15, k=(lane>>4)*8+e).
__global__ __launch_bounds__(256) void pack_wh(const float* __restrict__ W,
                                               f16* __restrict__ wpack) {
  int s = blockIdx.x * 256 + threadIdx.x;   // 0 .. 524287
  int lane = s & 63;
  int ks = (s >> 6) & 7;
  int ni = (s >> 9) & 3;
  int w  = (s >> 11) & 7;
  int cb = s >> 14;                          // 0..31
  int nh = w & 1, ksl = w >> 1;
  int c = nh * 64 + ni * 16 + (lane & 15);   // block-local col 0..127
  int g = c >> 5, ul = c & 31;
  int ncol = g * 1024 + cb * 32 + ul;        // global gate col
  int kb = ksl * 256 + ks * 32 + (lane >> 4) * 8;
  half8 v;
#pragma unroll
  for (int e = 0; e < 8; ++e)
    v[e] = (f16)W[(size_t)(512 + kb + e) * 4096 + ncol];
  ((half8*)wpack)[s] = v;
}

// ---------------- generic f16 MFMA GEMM: C = A[MxK] * Bt[NxK]^T + bias ----------------
template <typename OT>
__global__ __launch_bounds__(256) void gemm_f16(const f16* __restrict__ A,
                                                const f16* __restrict__ Bt,
                                                const float* __restrict__ bias,
                                                OT* __restrict__ C,
                                                int M, int N, int K) {
  __shared__ __align__(16) char smem[32768];   // As 16K | Bs 16K
  const int tid = threadIdx.x;
  const int n0 = blockIdx.x * 128, m0 = blockIdx.y * 128;
  const int l = tid & 63, w = tid >> 6;
  const int wr = w >> 1, wc = w & 1;
  const int r16 = l & 15, hi = l >> 4;
  floatx4 acc[4][4];
#pragma unroll
  for (int a = 0; a < 4; ++a)
#pragma unroll
    for (int b = 0; b < 4; ++b) acc[a][b] = (floatx4){0.f, 0.f, 0.f, 0.f};

  const int nk = K >> 6;
  for (int kk = 0; kk < nk; ++kk) {
    __syncthreads();
#pragma unroll
    for (int q = 0; q < 4; ++q) {
      int c = q * 256 + tid;
      int row = c >> 3, g8 = c & 7;
      gload_lds16(A + (size_t)(m0 + row) * K + kk * 64 + g8 * 8, smem + c * 16);
    }
#pragma unroll
    for (int q = 0; q < 4; ++q) {
      int c = q * 256 + tid;
      int row = c >> 3, g8 = c & 7;
      gload_lds16(Bt + (size_t)(n0 + row) * K + kk * 64 + g8 * 8, smem + 16384 + c * 16);
    }
    __syncthreads();
#pragma unroll
    for (int ks = 0; ks < 2; ++ks) {
      half8 af[4], bf[4];
#pragma unroll
      for (int mi = 0; mi < 4; ++mi)
        af[mi] = *(const half8*)(smem + ((wr * 64 + mi * 16 + r16) * 64 + ks * 32 + hi * 8) * 2);
#pragma unroll
      for (int ni = 0; ni < 4; ++ni)
        bf[ni] = *(const half8*)(smem + 16384 +
                                 ((wc * 64 + ni * 16 + r16) * 64 + ks * 32 + hi * 8) * 2);
#pragma unroll
      for (int mi = 0; mi < 4; ++mi)
#pragma unroll
        for (int ni = 0; ni < 4; ++ni)
          acc[mi][ni] = __builtin_amdgcn_mfma_f32_16x16x32_f16(af[mi], bf[ni], acc[mi][ni], 0, 0, 0);
    }
  }
#pragma unroll
  for (int ni = 0; ni < 4; ++ni) {
    int col = n0 + wc * 64 + ni * 16 + r16;
    float bv = bias[col];
#pragma unroll
    for (int mi = 0; mi < 4; ++mi)
#pragma unroll
      for (int rr = 0; rr < 4; ++rr) {
        int row = m0 + wr * 64 + mi * 16 + hi * 4 + rr;
        C[(size_t)row * N + col] = (OT)(acc[mi][ni][rr] + bv);
      }
  }
}

// ---------------- phase 2: persistent recurrent kernel ----------------
// grid 256 blocks x 512 threads. block bk: team = bk>>5 (16 batch rows),
// colblock cb = bk&31 (hidden units u0..u0+31 -> gate cols {g*1024+u0+ul}).
// wave w: ksl = w>>1 (K slice of 256), nh = w&1 (64-col half).
__global__ __launch_bounds__(512, 2)
void lstm_phase2(const f16* __restrict__ wpack, const f16* __restrict__ xw,
                 const float* __restrict__ c_in, const float* __restrict__ h_in,
                 const int* __restrict__ seq_lens,
                 unsigned* teamh,
                 float* __restrict__ lstm_out, f16* __restrict__ lstm16,
                 float* __restrict__ c_out, float* __restrict__ h_out) {
  __shared__ __align__(16) char smem[65536];   // h_lds 32K (swizzled) | red 32K (XOR-swizzled)
  const int tid = threadIdx.x;
  const int bk = blockIdx.x;
  const int team = bk >> 5, cb = bk & 31;
  const int b0 = team * 16;
  const int u0 = cb * 32;
  const int l = tid & 63, w = tid >> 6;
  const int nh = w & 1, ksl = w >> 1;
  const int r16 = l & 15, hi = l >> 4;

  // persistent W_h fragments: 32 x f16x8 = 128 regs (VGPR/AGPR unified)
  half8 wf[4][8];
  {
    const half8* wp = (const half8*)wpack;
    size_t base = (size_t)((cb * 8 + w) * 4) * 8 * 64;
#pragma unroll
    for (int ni = 0; ni < 4; ++ni)
#pragma unroll
      for (int ks = 0; ks < 8; ++ks)
        wf[ni][ks] = wp[base + (size_t)(ni * 8 + ks) * 64 + l];
  }

  const int bb = tid >> 5, ul = tid & 31;     // consumer identity: batch row, unit
  const int bglob = b0 + bb;
  const int nunit = u0 + ul;
  float creg = c_in[bglob * 1024 + nunit];
  float hreg = h_in[bglob * 1024 + nunit];
  const int slen = seq_lens[bglob];

  float* red = (float*)(smem + 32768);

  // per-thread staging granule offsets (u32 elements), constant across t
  int goff[4];
#pragma unroll
  for (int q = 0; q < 4; ++q) {
    int G = q * 512 + tid;
    int r = G >> 7, p = G & 127;
    int dg = p ^ (r & 7);               // inverse swizzle on SOURCE, linear LDS dest
    goff[q] = (b0 + r) * 1024 + dg * 8;
  }

#pragma unroll 1
  for (int t = 0; t < 512; ++t) {
    // prefetch this step's x-projection (normal cached loads, consumed at reduce)
    f16 xwv0, xwv1, xwv2, xwv3;
    {
      const f16* xp = xw + ((size_t)bglob * 512 + t) * 4096 + nunit;
      xwv0 = xp[0]; xwv1 = xp[1024]; xwv2 = xp[2048]; xwv3 = xp[3072];
    }

    if (t > 0) {
      // poll own tagged words until all 32 carry tag==t, then stage to LDS
      const unsigned* hb = teamh + (size_t)(t & 1) * 131072;
      const unsigned tt = (unsigned)t << 16;
      u32x4 a0, a1, b0v, b1v, c0v, c1v, d0v, d1v;
      while (true) {
        load_granule_coh(hb + goff[0], a0, a1);
        load_granule_coh(hb + goff[1], b0v, b1v);
        load_granule_coh(hb + goff[2], c0v, c1v);
        load_granule_coh(hb + goff[3], d0v, d1v);
        asm volatile("s_waitcnt vmcnt(0)" ::: "memory");
        unsigned bad = 0;
#define CHK(V) bad |= ((V.x ^ tt) | (V.y ^ tt) | (V.z ^ tt) | (V.w ^ tt)) & 0xffff0000u
        CHK(a0); CHK(a1); CHK(b0v); CHK(b1v); CHK(c0v); CHK(c1v); CHK(d0v); CHK(d1v);
#undef CHK
        if (bad == 0) break;
      }
      // strip tags: pack low halves pairwise into f16x8 granules, write linear LDS
#define PACK_WRITE(Q, LO, HI)                                                    \
      {                                                                          \
        u32x4 pk = {__builtin_amdgcn_perm(LO.y, LO.x, 0x05040100u),              \
                    __builtin_amdgcn_perm(LO.w, LO.z, 0x05040100u),              \
                    __builtin_amdgcn_perm(HI.y, HI.x, 0x05040100u),              \
                    __builtin_amdgcn_perm(HI.w, HI.z, 0x05040100u)};             \
        *(u32x4*)(smem + (Q * 512 + tid) * 16) = pk;                             \
      }
      PACK_WRITE(0, a0, a1); PACK_WRITE(1, b0v, b1v);
      PACK_WRITE(2, c0v, c1v); PACK_WRITE(3, d0v, d1v);
#undef PACK_WRITE
    } else {
      // first step: stage h_in (fp32 -> f16) with the same swizzle
#pragma unroll
      for (int q = 0; q < 4; ++q) {
        int G = q * 512 + tid;
        const float* s = h_in + goff[q];
        half8 v;
#pragma unroll
        for (int e = 0; e < 8; ++e) v[e] = (f16)s[e];
        *(half8*)(smem + G * 16) = v;
      }
    }
    __syncthreads();                     // bar1: LDS h staged

    // MFMA: gates_partial[16 x 64cols] over K slice of 256
    floatx4 acc0 = {0.f, 0.f, 0.f, 0.f}, acc1 = acc0, acc2 = acc0, acc3 = acc0;
#pragma unroll
    for (int ks = 0; ks < 8; ++ks) {
      int gran = ksl * 32 + ks * 4 + hi;
      int phys = gran ^ (r16 & 7);      // swizzled read -> conflict-free b128
      half8 a = *(const half8*)(smem + r16 * 2048 + phys * 16);
      acc0 = __builtin_amdgcn_mfma_f32_16x16x32_f16(a, wf[0][ks], acc0, 0, 0, 0);
      acc1 = __builtin_amdgcn_mfma_f32_16x16x32_f16(a, wf[1][ks], acc1, 0, 0, 0);
      acc2 = __builtin_amdgcn_mfma_f32_16x16x32_f16(a, wf[2][ks], acc2, 0, 0, 0);
      acc3 = __builtin_amdgcn_mfma_f32_16x16x32_f16(a, wf[3][ks], acc3, 0, 0, 0);
    }
    {
      int cbase = nh * 64 + r16;
      int rbase = ksl * 16 + hi * 4;
#pragma unroll
      for (int rr = 0; rr < 4; ++rr) {
        int rowr = rbase + rr;
        unsigned sw = (unsigned)(rowr & 7) << 2;   // bank XOR-swizzle (2 lanes/bank)
        float* rp = red + (size_t)rowr * 128;
        rp[(cbase + 0) ^ sw]  = acc0[rr];
        rp[(cbase + 16) ^ sw] = acc1[rr];
        rp[(cbase + 32) ^ sw] = acc2[rr];
        rp[(cbase + 48) ^ sw] = acc3[rr];
      }
    }
    __syncthreads();                     // bar2: red complete

    // reduce 4 K-slices + x-projection, then gate nonlinearities
    float g0 = (float)xwv0, g1 = (float)xwv1, g2 = (float)xwv2, g3 = (float)xwv3;
#pragma unroll
    for (int p = 0; p < 4; ++p) {
      int rowp = p * 16 + bb;
      unsigned sw = (unsigned)(rowp & 7) << 2;
      const float* rp = red + (size_t)rowp * 128;
      g0 += rp[(ul + 0) ^ sw];
      g1 += rp[(ul + 32) ^ sw];
      g2 += rp[(ul + 64) ^ sw];
      g3 += rp[(ul + 96) ^ sw];
    }
    float nc = creg * sigm(g2 + 1.f) + sigm(g0) * tanh_fast(g1);   // i,j,f,o order
    float nhv = tanh_fast(nc) * sigm(g3);
    bool valid = t < slen;
    if (valid) { creg = nc; hreg = nhv; }
    float outv = valid ? nhv : 0.f;
    size_t orow = ((size_t)bglob * 512 + t) * 1024 + nunit;

    // tagged h publish: fire-and-forget coherent store (tag = t+1)
    {
      unsigned hv = (unsigned)__builtin_bit_cast(unsigned short, (f16)hreg)
                  | ((unsigned)(t + 1) << 16);
      store_u32_coh(teamh + (size_t)((t + 1) & 1) * 131072 + bglob * 1024 + nunit, hv);
    }
    // bulk outputs: normal cached stores, written back lazily
    lstm_out[orow] = outv;
    lstm16[orow] = (f16)outv;
  }

  c_out[bglob * 1024 + nunit] = creg;
  h_out[bglob * 1024 + nunit] = hreg;
}

// ---------------- host ----------------
extern "C" void kernel_launch(void* const* d_in, const int* in_sizes, int n_in,
                              void* d_out, int out_size, void* d_ws, size_t ws_size,
                              hipStream_t stream) {
  const float* inputs  = (const float*)d_in[0];
  const float* c_in    = (const float*)d_in[1];
  const float* h_in    = (const float*)d_in[2];
  const float* W_lstm  = (const float*)d_in[3];
  const float* b_lstm  = (const float*)d_in[4];
  const float* W_out   = (const float*)d_in[5];
  const float* b_out   = (const float*)d_in[6];
  const int*   seq_lens= (const int*)d_in[7];

  float* logits  = (float*)d_out;
  float* lstm_out= logits + (size_t)65536 * 256;
  float* c_out   = lstm_out + (size_t)65536 * 1024;
  float* h_out   = c_out + (size_t)128 * 1024;

  if (ws_size < WS_NEED) return;   // fail visibly (poison stays) rather than corrupt

  char* ws = (char*)d_ws;
  f16* xw    = (f16*)(ws + XW_OFF);
  f16* in16  = (f16*)(ws + IN16_OFF);
  f16* l16   = (f16*)(ws + L16_OFF);
  f16* wxt   = (f16*)(ws + WXT_OFF);
  f16* wot   = (f16*)(ws + WOT_OFF);
  f16* wpk   = (f16*)(ws + WPK_OFF);
  unsigned* teamh = (unsigned*)(ws + TH_OFF);

  conv_f32_to_f16<<<16384, 256, 0, stream>>>(inputs, in16);
  transpose_f32_to_f16<<<dim3(64, 8), 256, 0, stream>>>(W_lstm, wxt, 512, 4096);
  transpose_f32_to_f16<<<dim3(4, 16), 256, 0, stream>>>(W_out, wot, 1024, 256);
  pack_wh<<<2048, 256, 0, stream>>>(W_lstm, wpk);

  // phase 1: xw = X @ W_x + b_lstm
  gemm_f16<f16><<<dim3(32, 512), 256, 0, stream>>>(in16, wxt, b_lstm, xw, 65536, 4096, 512);

  // phase 2: persistent recurrence (cooperative => co-residency guaranteed)
  {
    const f16* wpk_c = wpk;
    const f16* xw_c  = xw;
    void* args[] = {(void*)&wpk_c, (void*)&xw_c, (void*)&c_in, (void*)&h_in,
                    (void*)&seq_lens, (void*)&teamh,
                    (void*)&lstm_out, (void*)&l16, (void*)&c_out, (void*)&h_out};
    hipLaunchCooperativeKernel((void*)lstm_phase2, dim3(256), dim3(512), args, 0, stream);
  }

  // phase 3: logits = lstm_out @ W_out + b_out
  gemm_f16<float><<<dim3(2, 512), 256, 0, stream>>>(l16, wot, b_out, logits, 65536, 256, 1024);
}